// Round 3
// baseline (402.960 us; speedup 1.0000x reference)
//
#include <hip/hip_runtime.h>

// MultiHeadEMA, single-kernel 3-phase with software grid barrier. v3:
//   - 1024 blocks (4/CU) instead of 512 (2/CU): 2x waves for latency hiding
//   - G=32 (C=128): exactly ONE chunk per block -> minimal barrier skew,
//     E write-through traffic halved (33.5 -> 16.8 MB each way)
//   - ping-pong software pipeline on x loads (batch i+1 in flight during
//     compute of batch i) in phases 1 and 3
//
// Cross-block payloads (E/S) use sc0/sc1 write-through stores + bypass loads
// (coherence point; per-XCD L2 never holds them dirty) -- protocol verified
// correct in round 2.

#define BB 8
#define LL 4096
#define DD 1024
#define NN 16
#define UF 8

__device__ __forceinline__ float sigmoid_precise(float v) {
    return 1.0f / (1.0f + expf(-v));
}

// ---- coherent (sc0 sc1) asm memory ops: bypass non-coherent per-XCD L2 ----
__device__ __forceinline__ void sc_store(float* p, float v) {
    asm volatile("global_store_dword %0, %1, off sc0 sc1"
                 :: "v"(p), "v"(v) : "memory");
}
__device__ __forceinline__ int sc_load_i(const int* p) {
    int v;
    asm volatile("global_load_dword %0, %1, off sc0 sc1\n\t"
                 "s_waitcnt vmcnt(0)"
                 : "=v"(v) : "v"(p) : "memory");
    return v;
}
__device__ __forceinline__ void sc_load4(const float* p0, const float* p1,
                                         const float* p2, const float* p3,
                                         float& o0, float& o1, float& o2, float& o3) {
    asm volatile(
        "global_load_dword %0, %4, off sc0 sc1\n\t"
        "global_load_dword %1, %5, off sc0 sc1\n\t"
        "global_load_dword %2, %6, off sc0 sc1\n\t"
        "global_load_dword %3, %7, off sc0 sc1\n\t"
        "s_waitcnt vmcnt(0)"
        : "=&v"(o0), "=&v"(o1), "=&v"(o2), "=&v"(o3)
        : "v"(p0), "v"(p1), "v"(p2), "v"(p3)
        : "memory");
}
__device__ __forceinline__ void sc_load8s(const float* p, size_t stride, float* o) {
    const float* a0 = p;
    const float* a1 = p + stride;
    const float* a2 = p + 2 * stride;
    const float* a3 = p + 3 * stride;
    const float* a4 = p + 4 * stride;
    const float* a5 = p + 5 * stride;
    const float* a6 = p + 6 * stride;
    const float* a7 = p + 7 * stride;
    asm volatile(
        "global_load_dword %0, %8, off sc0 sc1\n\t"
        "global_load_dword %1, %9, off sc0 sc1\n\t"
        "global_load_dword %2, %10, off sc0 sc1\n\t"
        "global_load_dword %3, %11, off sc0 sc1\n\t"
        "global_load_dword %4, %12, off sc0 sc1\n\t"
        "global_load_dword %5, %13, off sc0 sc1\n\t"
        "global_load_dword %6, %14, off sc0 sc1\n\t"
        "global_load_dword %7, %15, off sc0 sc1\n\t"
        "s_waitcnt vmcnt(0)"
        : "=&v"(o[0]), "=&v"(o[1]), "=&v"(o[2]), "=&v"(o[3]),
          "=&v"(o[4]), "=&v"(o[5]), "=&v"(o[6]), "=&v"(o[7])
        : "v"(a0), "v"(a1), "v"(a2), "v"(a3),
          "v"(a4), "v"(a5), "v"(a6), "v"(a7)
        : "memory");
}
__device__ __forceinline__ void vm_drain() {
    asm volatile("s_waitcnt vmcnt(0)" ::: "memory");
}

template <int NB_>
__device__ __forceinline__ void grid_barrier(int* bar) {
    vm_drain();
    __syncthreads();
    if (threadIdx.x == 0) {
        atomicAdd(bar, 1);                       // device-scope (m20)
        while (sc_load_i(bar) < NB_)
            __builtin_amdgcn_s_sleep(2);
    }
    __syncthreads();
}

template <int G_, int NB_>
__global__ __launch_bounds__(256, 5) void ema_onepass(
    const float* __restrict__ x,
    const float* __restrict__ delta,
    const float* __restrict__ alpha,
    const float* __restrict__ beta,
    const float* __restrict__ gamma,
    const float* __restrict__ omega,
    float* __restrict__ out,
    float* __restrict__ E,        // [BB][G_][NN][DD], scanned in place
    int*   __restrict__ bar)      // [2] grid-barrier counters (memset 0)
{
    constexpr int C_ = LL / G_;
    static_assert(NB_ == 32 * G_, "one chunk-task per block");
    static_assert((C_ & (C_ - 1)) == 0, "C_ must be a power of two");

    const int blk   = blockIdx.x;
    const int chain = blk & 31;               // (b, dblk)
    const int g     = blk >> 5;
    const int b     = chain >> 2;
    const int dblk  = chain & 3;
    const int d     = dblk * 256 + threadIdx.x;

    float q[NN], gc[NN];
#pragma unroll
    for (int n = 0; n < NN; ++n) {
        const float p = sigmoid_precise(delta[d * NN + n]);
        const float a = sigmoid_precise(alpha[d * NN + n]);
        q[n]  = 1.0f - p * a;
        gc[n] = p * beta[d * NN + n] * gamma[d * NN + n] * 0.25f; // sqrt(1/16)
    }
    const float om = omega[d];

    const float* xp = x + ((size_t)b * LL + (size_t)g * C_) * DD + d;

    // ---- phase 1: local scan of one chunk; publish end state (write-through) -
    {
        float u[NN];
#pragma unroll
        for (int n = 0; n < NN; ++n) u[n] = 0.0f;

        float xa[UF], xb[UF];
#pragma unroll
        for (int j = 0; j < UF; ++j)
            xa[j] = xp[(size_t)j * DD];
        for (int ii = 0; ii < C_; ii += 2 * UF) {
#pragma unroll
            for (int j = 0; j < UF; ++j)                       // batch i+1 in flight
                xb[j] = xp[(size_t)(ii + UF + j) * DD];
#pragma unroll
            for (int j = 0; j < UF; ++j)                       // compute batch i
#pragma unroll
                for (int n = 0; n < NN; ++n)
                    u[n] = fmaf(q[n], u[n], xa[j]);
            if (ii + 2 * UF < C_) {
#pragma unroll
                for (int j = 0; j < UF; ++j)                   // batch i+2 in flight
                    xa[j] = xp[(size_t)(ii + 2 * UF + j) * DD];
            }
#pragma unroll
            for (int j = 0; j < UF; ++j)                       // compute batch i+1
#pragma unroll
                for (int n = 0; n < NN; ++n)
                    u[n] = fmaf(q[n], u[n], xb[j]);
        }

        float* Ep = E + (((size_t)b * G_ + g) * NN) * DD + d;
#pragma unroll
        for (int n = 0; n < NN; ++n)
            sc_store(Ep + (size_t)n * DD, u[n]);
    }

    grid_barrier<NB_>(&bar[0]);

    // ---- phase 2: carry scan across g, one thread per (b,n,d) ----
    if (blk * 256 < BB * NN * DD) {
        const int tt = blk * 256 + threadIdx.x;
        const int sd = tt & (DD - 1);
        const int sn = (tt >> 10) & (NN - 1);
        const int sb = tt >> 14;

        const float sp = sigmoid_precise(delta[sd * NN + sn]);
        const float sa = sigmoid_precise(alpha[sd * NN + sn]);
        const float sq = 1.0f - sp * sa;
        float Qc = sq;                                // q^C by repeated squaring
#pragma unroll
        for (int s2 = 1; s2 < C_; s2 <<= 1) Qc *= Qc;

        float* Ep = E + ((size_t)sb * G_ * NN + sn) * DD + sd;
        const size_t gs = (size_t)NN * DD;

        float u = 0.0f;
        for (int gg = 0; gg < G_; gg += UF) {
            float ev[UF];
            sc_load8s(Ep + (size_t)gg * gs, gs, ev);
            float sv[UF];
#pragma unroll
            for (int j = 0; j < UF; ++j) {
                u = fmaf(Qc, u, ev[j]);
                sv[j] = u;
            }
#pragma unroll
            for (int j = 0; j < UF; ++j)
                sc_store(Ep + (size_t)(gg + j) * gs, sv[j]);
        }
    }

    grid_barrier<NB_>(&bar[1]);

    // ---- phase 3: rescan seeded with S[g-1]; fused residual; write out ----
    {
        float u[NN];
        if (g > 0) {
            const float* Sp = E + (((size_t)b * G_ + (g - 1)) * NN) * DD + d;
#pragma unroll
            for (int n = 0; n < NN; n += 4)
                sc_load4(Sp + (size_t)(n + 0) * DD, Sp + (size_t)(n + 1) * DD,
                         Sp + (size_t)(n + 2) * DD, Sp + (size_t)(n + 3) * DD,
                         u[n + 0], u[n + 1], u[n + 2], u[n + 3]);
        } else {
#pragma unroll
            for (int n = 0; n < NN; ++n) u[n] = 0.0f;
        }

        float* op = out + ((size_t)b * LL + (size_t)g * C_) * DD + d;

        float xa[UF], xb[UF];
#pragma unroll
        for (int j = 0; j < UF; ++j)
            xa[j] = xp[(size_t)j * DD];
        for (int ii = 0; ii < C_; ii += 2 * UF) {
#pragma unroll
            for (int j = 0; j < UF; ++j)
                xb[j] = xp[(size_t)(ii + UF + j) * DD];
#pragma unroll
            for (int j = 0; j < UF; ++j) {
                const float xvj = xa[j];
                float a0 = om * xvj, a1 = 0.0f, a2 = 0.0f, a3 = 0.0f;
#pragma unroll
                for (int n = 0; n < NN; n += 4) {
                    u[n + 0] = fmaf(q[n + 0], u[n + 0], xvj);
                    u[n + 1] = fmaf(q[n + 1], u[n + 1], xvj);
                    u[n + 2] = fmaf(q[n + 2], u[n + 2], xvj);
                    u[n + 3] = fmaf(q[n + 3], u[n + 3], xvj);
                    a0 = fmaf(gc[n + 0], u[n + 0], a0);
                    a1 = fmaf(gc[n + 1], u[n + 1], a1);
                    a2 = fmaf(gc[n + 2], u[n + 2], a2);
                    a3 = fmaf(gc[n + 3], u[n + 3], a3);
                }
                op[(size_t)(ii + j) * DD] = (a0 + a1) + (a2 + a3);
            }
            if (ii + 2 * UF < C_) {
#pragma unroll
                for (int j = 0; j < UF; ++j)
                    xa[j] = xp[(size_t)(ii + 2 * UF + j) * DD];
            }
#pragma unroll
            for (int j = 0; j < UF; ++j) {
                const float xvj = xb[j];
                float a0 = om * xvj, a1 = 0.0f, a2 = 0.0f, a3 = 0.0f;
#pragma unroll
                for (int n = 0; n < NN; n += 4) {
                    u[n + 0] = fmaf(q[n + 0], u[n + 0], xvj);
                    u[n + 1] = fmaf(q[n + 1], u[n + 1], xvj);
                    u[n + 2] = fmaf(q[n + 2], u[n + 2], xvj);
                    u[n + 3] = fmaf(q[n + 3], u[n + 3], xvj);
                    a0 = fmaf(gc[n + 0], u[n + 0], a0);
                    a1 = fmaf(gc[n + 1], u[n + 1], a1);
                    a2 = fmaf(gc[n + 2], u[n + 2], a2);
                    a3 = fmaf(gc[n + 3], u[n + 3], a3);
                }
                op[(size_t)(ii + UF + j) * DD] = (a0 + a1) + (a2 + a3);
            }
        }
    }
}

extern "C" void kernel_launch(void* const* d_in, const int* in_sizes, int n_in,
                              void* d_out, int out_size, void* d_ws, size_t ws_size,
                              hipStream_t stream) {
    const float* x     = (const float*)d_in[0];
    const float* delta = (const float*)d_in[1];
    const float* alpha = (const float*)d_in[2];
    const float* beta  = (const float*)d_in[3];
    const float* gamma = (const float*)d_in[4];
    const float* omega = (const float*)d_in[5];
    float* out = (float*)d_out;

    int*   bar = (int*)d_ws;
    float* E   = (float*)((char*)d_ws + 256);

    hipMemsetAsync(d_ws, 0, 256, stream);   // reset barrier counters

    const size_t need32 = 256 + (size_t)BB * 32 * NN * DD * sizeof(float);
    if (ws_size >= need32)
        hipLaunchKernelGGL((ema_onepass<32, 1024>), dim3(1024), dim3(256), 0,
                           stream, x, delta, alpha, beta, gamma, omega, out, E, bar);
    else
        hipLaunchKernelGGL((ema_onepass<16, 512>), dim3(512), dim3(256), 0,
                           stream, x, delta, alpha, beta, gamma, omega, out, E, bar);
}

// Round 4
// 348.362 us; speedup vs baseline: 1.1567x; 1.1567x over previous
//
#include <hip/hip_runtime.h>

// MultiHeadEMA, single-kernel 3-phase with software grid barrier. v4:
//   - back to v2 skeleton: 512 blocks (2/CU), launch_bounds(256,2) -> VGPR
//     budget 256, NO spills (v3's launch_bounds(256,5)/48-VGPR spilled to
//     scratch: +48MB WRITE, the round-3 regression)
//   - dual-stream (chunks g and g+32 processed concurrently) x double-batch
//     pipeline: 16-32 outstanding loads/wave while computing -> per-CU
//     in-flight ~48KB > ~22KB needed to cover HBM latency -> BW-bound
//   - phase-3 carry-in via 2x sc_load8s (2 coherent round-trips, was 4)
//
// Cross-block payloads (E/S) use sc0/sc1 write-through stores + bypass loads
// (coherence point; per-XCD L2 never holds them dirty) -- protocol verified
// correct in rounds 2-3.

#define BB 8
#define LL 4096
#define DD 1024
#define NN 16
#define UF 8
#define NB 512          // grid blocks; 2/CU -- residency-safe for the barrier

__device__ __forceinline__ float sigmoid_precise(float v) {
    return 1.0f / (1.0f + expf(-v));
}

// ---- coherent (sc0 sc1) asm memory ops: bypass non-coherent per-XCD L2 ----
__device__ __forceinline__ void sc_store(float* p, float v) {
    asm volatile("global_store_dword %0, %1, off sc0 sc1"
                 :: "v"(p), "v"(v) : "memory");
}
__device__ __forceinline__ int sc_load_i(const int* p) {
    int v;
    asm volatile("global_load_dword %0, %1, off sc0 sc1\n\t"
                 "s_waitcnt vmcnt(0)"
                 : "=v"(v) : "v"(p) : "memory");
    return v;
}
__device__ __forceinline__ void sc_load8s(const float* p, size_t stride, float* o) {
    const float* a0 = p;
    const float* a1 = p + stride;
    const float* a2 = p + 2 * stride;
    const float* a3 = p + 3 * stride;
    const float* a4 = p + 4 * stride;
    const float* a5 = p + 5 * stride;
    const float* a6 = p + 6 * stride;
    const float* a7 = p + 7 * stride;
    asm volatile(
        "global_load_dword %0, %8, off sc0 sc1\n\t"
        "global_load_dword %1, %9, off sc0 sc1\n\t"
        "global_load_dword %2, %10, off sc0 sc1\n\t"
        "global_load_dword %3, %11, off sc0 sc1\n\t"
        "global_load_dword %4, %12, off sc0 sc1\n\t"
        "global_load_dword %5, %13, off sc0 sc1\n\t"
        "global_load_dword %6, %14, off sc0 sc1\n\t"
        "global_load_dword %7, %15, off sc0 sc1\n\t"
        "s_waitcnt vmcnt(0)"
        : "=&v"(o[0]), "=&v"(o[1]), "=&v"(o[2]), "=&v"(o[3]),
          "=&v"(o[4]), "=&v"(o[5]), "=&v"(o[6]), "=&v"(o[7])
        : "v"(a0), "v"(a1), "v"(a2), "v"(a3),
          "v"(a4), "v"(a5), "v"(a6), "v"(a7)
        : "memory");
}
__device__ __forceinline__ void vm_drain() {
    asm volatile("s_waitcnt vmcnt(0)" ::: "memory");
}

template <int NB_>
__device__ __forceinline__ void grid_barrier(int* bar) {
    vm_drain();
    __syncthreads();
    if (threadIdx.x == 0) {
        atomicAdd(bar, 1);                       // device-scope (m20)
        while (sc_load_i(bar) < NB_)
            __builtin_amdgcn_s_sleep(2);
    }
    __syncthreads();
}

template <int G_>
__global__ __launch_bounds__(256, 2) void ema_onepass(
    const float* __restrict__ x,
    const float* __restrict__ delta,
    const float* __restrict__ alpha,
    const float* __restrict__ beta,
    const float* __restrict__ gamma,
    const float* __restrict__ omega,
    float* __restrict__ out,
    float* __restrict__ E,        // [BB][G_][NN][DD], scanned in place
    int*   __restrict__ bar)      // [2] grid-barrier counters (memset 0)
{
    constexpr int C_    = LL / G_;
    constexpr int NPAIR = G_ / 32;            // chunk-pairs per block
    static_assert(32 * G_ == NB * 2 * NPAIR, "pair tiling must be exact");
    static_assert((C_ & (C_ - 1)) == 0, "C_ must be a power of two");

    const int blk   = blockIdx.x;
    const int chain = blk & 31;               // (b, dblk)
    const int gbase = blk >> 5;               // [0,16)
    const int b     = chain >> 2;
    const int dblk  = chain & 3;
    const int d     = dblk * 256 + threadIdx.x;

    float q[NN];
#pragma unroll
    for (int n = 0; n < NN; ++n) {
        const float p = sigmoid_precise(delta[d * NN + n]);
        const float a = sigmoid_precise(alpha[d * NN + n]);
        q[n] = 1.0f - p * a;
    }

    // ---- phase 1: dual-stream pipelined local scans; publish end states ----
    for (int p = 0; p < NPAIR; ++p) {
        const int gA = gbase + p * 16;
        const int gB = gA + G_ / 2;
        const float* xA = x + ((size_t)b * LL + (size_t)gA * C_) * DD + d;
        const float* xB = x + ((size_t)b * LL + (size_t)gB * C_) * DD + d;

        float ua[NN], ub[NN];
#pragma unroll
        for (int n = 0; n < NN; ++n) { ua[n] = 0.0f; ub[n] = 0.0f; }

        float a0[UF], b0[UF], a1[UF], b1[UF];
#pragma unroll
        for (int j = 0; j < UF; ++j) a0[j] = xA[(size_t)j * DD];
#pragma unroll
        for (int j = 0; j < UF; ++j) b0[j] = xB[(size_t)j * DD];
#pragma unroll
        for (int j = 0; j < UF; ++j) a1[j] = xA[(size_t)(UF + j) * DD];
#pragma unroll
        for (int j = 0; j < UF; ++j) b1[j] = xB[(size_t)(UF + j) * DD];

        for (int ii = 0; ii < C_; ii += 2 * UF) {
#pragma unroll
            for (int j = 0; j < UF; ++j)
#pragma unroll
                for (int n = 0; n < NN; ++n) ua[n] = fmaf(q[n], ua[n], a0[j]);
#pragma unroll
            for (int j = 0; j < UF; ++j)
#pragma unroll
                for (int n = 0; n < NN; ++n) ub[n] = fmaf(q[n], ub[n], b0[j]);
            if (ii + 2 * UF < C_) {
#pragma unroll
                for (int j = 0; j < UF; ++j) a0[j] = xA[(size_t)(ii + 2 * UF + j) * DD];
#pragma unroll
                for (int j = 0; j < UF; ++j) b0[j] = xB[(size_t)(ii + 2 * UF + j) * DD];
            }
#pragma unroll
            for (int j = 0; j < UF; ++j)
#pragma unroll
                for (int n = 0; n < NN; ++n) ua[n] = fmaf(q[n], ua[n], a1[j]);
#pragma unroll
            for (int j = 0; j < UF; ++j)
#pragma unroll
                for (int n = 0; n < NN; ++n) ub[n] = fmaf(q[n], ub[n], b1[j]);
            if (ii + 3 * UF < C_) {
#pragma unroll
                for (int j = 0; j < UF; ++j) a1[j] = xA[(size_t)(ii + 3 * UF + j) * DD];
#pragma unroll
                for (int j = 0; j < UF; ++j) b1[j] = xB[(size_t)(ii + 3 * UF + j) * DD];
            }
        }

        float* EpA = E + (((size_t)b * G_ + gA) * NN) * DD + d;
        float* EpB = E + (((size_t)b * G_ + gB) * NN) * DD + d;
#pragma unroll
        for (int n = 0; n < NN; ++n) sc_store(EpA + (size_t)n * DD, ua[n]);
#pragma unroll
        for (int n = 0; n < NN; ++n) sc_store(EpB + (size_t)n * DD, ub[n]);
    }

    grid_barrier<NB>(&bar[0]);

    // ---- phase 2: carry scan across g, one thread per (b,n,d) ----
    {
        const int tt = blk * 256 + threadIdx.x;       // exactly BB*NN*DD threads
        const int sd = tt & (DD - 1);
        const int sn = (tt >> 10) & (NN - 1);
        const int sb = tt >> 14;

        const float sp = sigmoid_precise(delta[sd * NN + sn]);
        const float sa = sigmoid_precise(alpha[sd * NN + sn]);
        const float sq = 1.0f - sp * sa;
        float Qc = sq;                                // q^C by repeated squaring
#pragma unroll
        for (int s2 = 1; s2 < C_; s2 <<= 1) Qc *= Qc;

        float* Ep = E + ((size_t)sb * G_ * NN + sn) * DD + sd;
        const size_t gs = (size_t)NN * DD;

        float u = 0.0f;
        for (int gg = 0; gg < G_; gg += UF) {
            float ev[UF];
            sc_load8s(Ep + (size_t)gg * gs, gs, ev);
            float sv[UF];
#pragma unroll
            for (int j = 0; j < UF; ++j) {
                u = fmaf(Qc, u, ev[j]);
                sv[j] = u;
            }
#pragma unroll
            for (int j = 0; j < UF; ++j)
                sc_store(Ep + (size_t)(gg + j) * gs, sv[j]);
        }
    }

    grid_barrier<NB>(&bar[1]);

    // ---- phase 3: dual-stream pipelined rescan + fused residual + store ----
    float gc[NN];
#pragma unroll
    for (int n = 0; n < NN; ++n) {
        const float p = sigmoid_precise(delta[d * NN + n]);
        gc[n] = p * beta[d * NN + n] * gamma[d * NN + n] * 0.25f; // sqrt(1/16)
    }
    const float om = omega[d];

    for (int p = 0; p < NPAIR; ++p) {
        const int gA = gbase + p * 16;
        const int gB = gA + G_ / 2;
        const float* xA = x + ((size_t)b * LL + (size_t)gA * C_) * DD + d;
        const float* xB = x + ((size_t)b * LL + (size_t)gB * C_) * DD + d;
        float* oA = out + ((size_t)b * LL + (size_t)gA * C_) * DD + d;
        float* oB = out + ((size_t)b * LL + (size_t)gB * C_) * DD + d;

        float ua[NN], ub[NN];
        if (gA > 0) {
            const float* Sp = E + (((size_t)b * G_ + (gA - 1)) * NN) * DD + d;
            sc_load8s(Sp, (size_t)DD, ua);
            sc_load8s(Sp + (size_t)8 * DD, (size_t)DD, ua + 8);
        } else {
#pragma unroll
            for (int n = 0; n < NN; ++n) ua[n] = 0.0f;
        }
        {   // gB = gA + G_/2 >= 16 > 0 always
            const float* Sp = E + (((size_t)b * G_ + (gB - 1)) * NN) * DD + d;
            sc_load8s(Sp, (size_t)DD, ub);
            sc_load8s(Sp + (size_t)8 * DD, (size_t)DD, ub + 8);
        }

        float a0[UF], b0[UF], a1[UF], b1[UF];
#pragma unroll
        for (int j = 0; j < UF; ++j) a0[j] = xA[(size_t)j * DD];
#pragma unroll
        for (int j = 0; j < UF; ++j) b0[j] = xB[(size_t)j * DD];
#pragma unroll
        for (int j = 0; j < UF; ++j) a1[j] = xA[(size_t)(UF + j) * DD];
#pragma unroll
        for (int j = 0; j < UF; ++j) b1[j] = xB[(size_t)(UF + j) * DD];

        for (int ii = 0; ii < C_; ii += 2 * UF) {
#pragma unroll
            for (int j = 0; j < UF; ++j) {
                const float xv = a0[j];
                float s0 = om * xv, s1 = 0.0f, s2 = 0.0f, s3 = 0.0f;
#pragma unroll
                for (int n = 0; n < NN; n += 4) {
                    ua[n + 0] = fmaf(q[n + 0], ua[n + 0], xv);
                    ua[n + 1] = fmaf(q[n + 1], ua[n + 1], xv);
                    ua[n + 2] = fmaf(q[n + 2], ua[n + 2], xv);
                    ua[n + 3] = fmaf(q[n + 3], ua[n + 3], xv);
                    s0 = fmaf(gc[n + 0], ua[n + 0], s0);
                    s1 = fmaf(gc[n + 1], ua[n + 1], s1);
                    s2 = fmaf(gc[n + 2], ua[n + 2], s2);
                    s3 = fmaf(gc[n + 3], ua[n + 3], s3);
                }
                oA[(size_t)(ii + j) * DD] = (s0 + s1) + (s2 + s3);
            }
#pragma unroll
            for (int j = 0; j < UF; ++j) {
                const float xv = b0[j];
                float s0 = om * xv, s1 = 0.0f, s2 = 0.0f, s3 = 0.0f;
#pragma unroll
                for (int n = 0; n < NN; n += 4) {
                    ub[n + 0] = fmaf(q[n + 0], ub[n + 0], xv);
                    ub[n + 1] = fmaf(q[n + 1], ub[n + 1], xv);
                    ub[n + 2] = fmaf(q[n + 2], ub[n + 2], xv);
                    ub[n + 3] = fmaf(q[n + 3], ub[n + 3], xv);
                    s0 = fmaf(gc[n + 0], ub[n + 0], s0);
                    s1 = fmaf(gc[n + 1], ub[n + 1], s1);
                    s2 = fmaf(gc[n + 2], ub[n + 2], s2);
                    s3 = fmaf(gc[n + 3], ub[n + 3], s3);
                }
                oB[(size_t)(ii + j) * DD] = (s0 + s1) + (s2 + s3);
            }
            if (ii + 2 * UF < C_) {
#pragma unroll
                for (int j = 0; j < UF; ++j) a0[j] = xA[(size_t)(ii + 2 * UF + j) * DD];
#pragma unroll
                for (int j = 0; j < UF; ++j) b0[j] = xB[(size_t)(ii + 2 * UF + j) * DD];
            }
#pragma unroll
            for (int j = 0; j < UF; ++j) {
                const float xv = a1[j];
                float s0 = om * xv, s1 = 0.0f, s2 = 0.0f, s3 = 0.0f;
#pragma unroll
                for (int n = 0; n < NN; n += 4) {
                    ua[n + 0] = fmaf(q[n + 0], ua[n + 0], xv);
                    ua[n + 1] = fmaf(q[n + 1], ua[n + 1], xv);
                    ua[n + 2] = fmaf(q[n + 2], ua[n + 2], xv);
                    ua[n + 3] = fmaf(q[n + 3], ua[n + 3], xv);
                    s0 = fmaf(gc[n + 0], ua[n + 0], s0);
                    s1 = fmaf(gc[n + 1], ua[n + 1], s1);
                    s2 = fmaf(gc[n + 2], ua[n + 2], s2);
                    s3 = fmaf(gc[n + 3], ua[n + 3], s3);
                }
                oA[(size_t)(ii + UF + j) * DD] = (s0 + s1) + (s2 + s3);
            }
#pragma unroll
            for (int j = 0; j < UF; ++j) {
                const float xv = b1[j];
                float s0 = om * xv, s1 = 0.0f, s2 = 0.0f, s3 = 0.0f;
#pragma unroll
                for (int n = 0; n < NN; n += 4) {
                    ub[n + 0] = fmaf(q[n + 0], ub[n + 0], xv);
                    ub[n + 1] = fmaf(q[n + 1], ub[n + 1], xv);
                    ub[n + 2] = fmaf(q[n + 2], ub[n + 2], xv);
                    ub[n + 3] = fmaf(q[n + 3], ub[n + 3], xv);
                    s0 = fmaf(gc[n + 0], ub[n + 0], s0);
                    s1 = fmaf(gc[n + 1], ub[n + 1], s1);
                    s2 = fmaf(gc[n + 2], ub[n + 2], s2);
                    s3 = fmaf(gc[n + 3], ub[n + 3], s3);
                }
                oB[(size_t)(ii + UF + j) * DD] = (s0 + s1) + (s2 + s3);
            }
            if (ii + 3 * UF < C_) {
#pragma unroll
                for (int j = 0; j < UF; ++j) a1[j] = xA[(size_t)(ii + 3 * UF + j) * DD];
#pragma unroll
                for (int j = 0; j < UF; ++j) b1[j] = xB[(size_t)(ii + 3 * UF + j) * DD];
            }
        }
    }
}

extern "C" void kernel_launch(void* const* d_in, const int* in_sizes, int n_in,
                              void* d_out, int out_size, void* d_ws, size_t ws_size,
                              hipStream_t stream) {
    const float* x     = (const float*)d_in[0];
    const float* delta = (const float*)d_in[1];
    const float* alpha = (const float*)d_in[2];
    const float* beta  = (const float*)d_in[3];
    const float* gamma = (const float*)d_in[4];
    const float* omega = (const float*)d_in[5];
    float* out = (float*)d_out;

    int*   bar = (int*)d_ws;
    float* E   = (float*)((char*)d_ws + 256);

    hipMemsetAsync(d_ws, 0, 256, stream);   // reset barrier counters

    const size_t need64 = 256 + (size_t)BB * 64 * NN * DD * sizeof(float);
    if (ws_size >= need64)
        hipLaunchKernelGGL(ema_onepass<64>, dim3(NB), dim3(256), 0, stream,
                           x, delta, alpha, beta, gamma, omega, out, E, bar);
    else
        hipLaunchKernelGGL(ema_onepass<32>, dim3(NB), dim3(256), 0, stream,
                           x, delta, alpha, beta, gamma, omega, out, E, bar);
}